// Round 3
// baseline (4619.876 us; speedup 1.0000x reference)
//
#include <hip/hip_runtime.h>
#include <math.h>

// Shapes (fixed per reference setup_inputs):
#define BB 32
#define SFULL 513
#define TT 512
#define DD 1024
#define KK 256
#define VV 256
#define HH 2048
#define OO 256

// ---------------------------------------------------------------------------
// 128x128-tile GEMM: C[m][n] = sum_k A[m][k] * B[n][k]   (A * B^T)
// BK=16, 256 threads, 8x8 micro-tile, accumulate in CT (double for decision
// path, float for xV). int4-vectorized global staging; contiguous 8-element
// LDS fragments so reads become ds_read_b128. FMA-bound for fp64:
// per k-step 256 cyc fp64 FMA vs ~100 cyc LDS.
// ---------------------------------------------------------------------------
template <typename AT, typename BT, typename CT>
__global__ __launch_bounds__(256, 2) void gemm128(
    const AT* __restrict__ A, long long aBatch, int aPitch,
    const BT* __restrict__ Bm, long long bBatch, int bPitch,
    CT* __restrict__ C, long long cBatch, int cPitch, int Kd) {
  const int bz = blockIdx.z;
  A  += (size_t)bz * aBatch;
  Bm += (size_t)bz * bBatch;
  C  += (size_t)bz * cBatch;
  const int m0 = blockIdx.y * 128;
  const int n0 = blockIdx.x * 128;
  const int tid = threadIdx.x;
  const int tx = tid & 15;        // n micro-group
  const int ty = tid >> 4;        // m micro-group
  const int r  = tid >> 1;        // 0..127 staging row
  const int cb = (tid & 1) * 8;   // staging col block (0 or 8)

  __shared__ AT As[16][128];
  __shared__ BT Bs[16][128];

  CT acc[8][8];
#pragma unroll
  for (int i = 0; i < 8; i++)
#pragma unroll
    for (int j = 0; j < 8; j++) acc[i][j] = (CT)0;

  constexpr int CHA = 16 / sizeof(AT);  // elems per int4
  constexpr int CHB = 16 / sizeof(BT);

  for (int kk = 0; kk < Kd; kk += 16) {
    alignas(16) AT a8[8];
    alignas(16) BT b8[8];
    const AT* ag = A  + (size_t)(m0 + r) * aPitch + kk + cb;
    const BT* bg = Bm + (size_t)(n0 + r) * bPitch + kk + cb;
#pragma unroll
    for (int c = 0; c < 8 / CHA; c++)
      *(int4*)&a8[c * CHA] = *(const int4*)(ag + c * CHA);
#pragma unroll
    for (int c = 0; c < 8 / CHB; c++)
      *(int4*)&b8[c * CHB] = *(const int4*)(bg + c * CHB);
#pragma unroll
    for (int j = 0; j < 8; j++) As[cb + j][r] = a8[j];
#pragma unroll
    for (int j = 0; j < 8; j++) Bs[cb + j][r] = b8[j];
    __syncthreads();
#pragma unroll
    for (int k = 0; k < 16; k++) {
      CT av[8], bv[8];
#pragma unroll
      for (int i = 0; i < 8; i++) av[i] = (CT)As[k][ty * 8 + i];
#pragma unroll
      for (int j = 0; j < 8; j++) bv[j] = (CT)Bs[k][tx * 8 + j];
#pragma unroll
      for (int i = 0; i < 8; i++)
#pragma unroll
        for (int j = 0; j < 8; j++) acc[i][j] += av[i] * bv[j];
    }
    __syncthreads();
  }

#pragma unroll
  for (int i = 0; i < 8; i++) {
    CT* cp = C + (size_t)(m0 + ty * 8 + i) * cPitch + n0 + tx * 8;
#pragma unroll
    for (int j = 0; j < 8; j++) cp[j] = acc[i][j];
  }
}

// ---------------------------------------------------------------------------
// xQ = x[:, 512, :] @ W_Q^T   (fp32).
// ---------------------------------------------------------------------------
__global__ __launch_bounds__(256) void xq_kernel(const float* __restrict__ x,
                                                 const float* __restrict__ W_Q,
                                                 float* __restrict__ xQws,
                                                 float* __restrict__ outp) {
  const int b = blockIdx.x;
  const int tid = threadIdx.x;
  const int w = tid >> 6, lane = tid & 63;
  const float* xr = x + ((size_t)b * SFULL + TT) * DD;
  for (int n = w; n < KK; n += 4) {
    const float* wq = W_Q + (size_t)n * DD;
    float s = 0.f;
    for (int k = lane; k < DD; k += 64) s += wq[k] * xr[k];
#pragma unroll
    for (int off = 32; off; off >>= 1) s += __shfl_down(s, off);
    if (lane == 0) {
      xQws[b * KK + n] = s;
      outp[BB * OO + BB * DD + b * KK + n] = s;  // third output region
    }
  }
}

// ---------------------------------------------------------------------------
// Sequential winner-take-all scan — ONE WAVE per batch, NO barriers.
// 64 lanes x 32 head-slots each. Register pipeline depth 2: refill for step
// s+2 is issued before step s's shuffle reduce, so loads get ~2 step-bodies
// of latency hiding and nothing (no __syncthreads -> no vmcnt(0) drain) can
// force them to retire early. The refill misses winners of steps s, s+1;
// at consume those <=2 stale heads are excluded (scalar slot compare +
// per-lane owner mask) and their true values Gram[s][s-1] / Gram[s][s-2]
// (addresses known ahead of identity!) are injected as explicit candidates.
// Same fp64 values compared => bit-identical lastmap vs previous rounds.
// Requires Gram to live at a fixed element offset from L0t (ws layout).
// ---------------------------------------------------------------------------
__global__ __launch_bounds__(64, 1) void scan_kernel(const double* __restrict__ L0t,
                                                     const double* __restrict__ Gram,
                                                     int* __restrict__ lastmap) {
  const int b = blockIdx.x;
  const int lane = threadIdx.x;
  const double* base = L0t + (size_t)b * TT * HH;  // batch-b L0 base
  // element offset from `base` to batch-b Gram (fits int: max ~42M elems)
  const int goff = (int)((Gram - L0t) + (long long)b * TT * TT - (long long)b * TT * HH);

  int lastr[32];
#pragma unroll
  for (int i = 0; i < 32; i++) lastr[i] = -1;
  double buf[2][32];
  double gb1[2], gb2[2];

  // prologue: steps 0,1 are pure-L0 reads
#pragma unroll
  for (int p = 0; p < 2; p++) {
#pragma unroll
    for (int i = 0; i < 32; i++) buf[p][i] = base[p * HH + i * 64 + lane];
    gb1[p] = (p >= 1) ? base[goff + p * TT + (p - 1)] : 0.0;
    gb2[p] = 0.0;
  }

  int w1 = -1, w2 = -1;  // winners of steps s-1, s-2
  for (int T = 0; T < TT; T += 2) {
#pragma unroll
    for (int p = 0; p < 2; p++) {
      const int s = T + p;
      // ---- consume slot p: local argmax with stale-head exclusion
      const int slot1 = (w1 >= 0) ? (w1 >> 6) : -1;
      const int slot2 = (w2 >= 0) ? (w2 >> 6) : -1;
      const bool own1 = (w1 >= 0) && (lane == (w1 & 63));
      const bool own2 = (w2 >= 0) && (lane == (w2 & 63));
      double v = -INFINITY;
      int idx = 0x7fffffff;
#pragma unroll
      for (int i = 0; i < 32; i++) {
        const bool excl = (own1 && i == slot1) || (own2 && i == slot2);
        const double vi = excl ? -INFINITY : buf[p][i];
        if (vi > v) { v = vi; idx = i * 64 + lane; }  // ascending i: ties -> lowest h
      }
      // patched candidates for the stale heads (true current values)
      if (w1 >= 0) {
        const double c = gb1[p];
        if (c > v || (c == v && w1 < idx)) { v = c; idx = w1; }
      }
      if (w2 >= 0 && w2 != w1) {
        const double c = gb2[p];
        if (c > v || (c == v && w2 < idx)) { v = c; idx = w2; }
      }
      // ---- refill slot p for step f = s+2 (issued BEFORE the reduce;
      //      lastr holds winners <= s-1, so consume-side stale set is
      //      exactly {winner(s), winner(s+1)} = {w2, w1} at that time)
      const int f = s + 2;
      if (f < TT) {
        const int fH = f * HH;
        const int fT = goff + f * TT;
#pragma unroll
        for (int i = 0; i < 32; i++) {
          const int li = lastr[i];
          const int off = (li >= 0) ? (fT + li) : (fH + i * 64 + lane);
          buf[p][i] = base[off];
        }
        gb1[p] = base[fT + (f - 1)];
        gb2[p] = base[fT + (f - 2)];
      }
      // ---- 64-lane butterfly argmax (value, index) — no LDS, no barrier
#pragma unroll
      for (int off = 1; off < 64; off <<= 1) {
        const double ov = __shfl_xor(v, off);
        const int oi = __shfl_xor(idx, off);
        if (ov > v || (ov == v && oi < idx)) { v = ov; idx = oi; }
      }
      // ---- commit winner of step s
      w2 = w1;
      w1 = idx;
      const int slotn = idx >> 6;
      const bool ownn = (lane == (idx & 63));
#pragma unroll
      for (int i = 0; i < 32; i++)
        if (ownn && i == slotn) lastr[i] = s;
    }
  }
#pragma unroll
  for (int i = 0; i < 32; i++)
    lastmap[b * HH + i * 64 + lane] = lastr[i];
}

// ---------------------------------------------------------------------------
// Epilogue stage 1: q-logits, softmax -> hv; emit hvm (masked hv for
// untouched rows) and wgt[s] (hv of the row whose final content is step s).
// ---------------------------------------------------------------------------
__global__ __launch_bounds__(1024) void epi1_kernel(const float* __restrict__ W_hi0,
                                                    const double* __restrict__ xK64,
                                                    const float* __restrict__ xQws,
                                                    const int* __restrict__ lastmap,
                                                    float* __restrict__ hvmg,
                                                    float* __restrict__ wgtg) {
  const int b = blockIdx.x;
  const int tid = threadIdx.x;
  const int w = tid >> 6, lane = tid & 63;
  __shared__ float xq[KK];
  __shared__ float ql[HH];
  __shared__ float red[16];
  __shared__ float redsum[16];
  if (tid < KK) xq[tid] = xQws[b * KK + tid];
  if (tid < TT) wgtg[b * TT + tid] = 0.f;
  __syncthreads();

  for (int h = w; h < HH; h += 16) {
    int li = lastmap[b * HH + h];
    float s = 0.f;
    if (li < 0) {
      const float* p = W_hi0 + ((size_t)b * HH + h) * KK;
      for (int k = lane; k < KK; k += 64) s += p[k] * xq[k];
    } else {
      const double* p = xK64 + ((size_t)b * TT + li) * KK;
      for (int k = lane; k < KK; k += 64) s += (float)p[k] * xq[k];
    }
#pragma unroll
    for (int off = 32; off; off >>= 1) s += __shfl_down(s, off);
    if (lane == 0) ql[h] = s;
  }
  __syncthreads();

  // softmax over 2048
  float lm = fmaxf(ql[tid], ql[tid + 1024]);
#pragma unroll
  for (int off = 32; off; off >>= 1) lm = fmaxf(lm, __shfl_down(lm, off));
  if (lane == 0) red[w] = lm;
  __syncthreads();
  if (tid == 0) {
    float m = red[0];
    for (int i = 1; i < 16; i++) m = fmaxf(m, red[i]);
    red[0] = m;
  }
  __syncthreads();
  const float mx = red[0];
  float e1 = expf(ql[tid] - mx);
  float e2 = expf(ql[tid + 1024] - mx);
  float ls = e1 + e2;
#pragma unroll
  for (int off = 32; off; off >>= 1) ls += __shfl_down(ls, off);
  if (lane == 0) redsum[w] = ls;
  __syncthreads();
  if (tid == 0) {
    float s = 0.f;
    for (int i = 0; i < 16; i++) s += redsum[i];
    redsum[0] = s;
  }
  __syncthreads();
  const float inv = 1.f / redsum[0];
  const float hv1 = e1 * inv, hv2 = e2 * inv;
  const int li1 = lastmap[b * HH + tid];
  const int li2 = lastmap[b * HH + tid + 1024];
  hvmg[b * HH + tid] = (li1 < 0) ? hv1 : 0.f;
  hvmg[b * HH + tid + 1024] = (li2 < 0) ? hv2 : 0.f;
  if (li1 >= 0) wgtg[b * TT + li1] = hv1;  // last is injective: no races
  if (li2 >= 0) wgtg[b * TT + li2] = hv2;
}

// ---------------------------------------------------------------------------
// Epilogue stage 2: reinst_context[b,d] = sum_h hvm[h]*W_reinst0[b,h,d]
//                                       + sum_s wgt[s]*ctx[b,s,d]
// ---------------------------------------------------------------------------
__global__ __launch_bounds__(256) void epi2_kernel(const float* __restrict__ W_reinst0,
                                                   const float* __restrict__ x,
                                                   const float* __restrict__ hvmg,
                                                   const float* __restrict__ wgtg,
                                                   float* __restrict__ outp) {
  const int b = blockIdx.y;
  const int tid = threadIdx.x;
  const int d = blockIdx.x * 256 + tid;
  __shared__ float hvm[HH];
  __shared__ float wgt[TT];
  for (int i = tid; i < HH; i += 256) hvm[i] = hvmg[b * HH + i];
  for (int i = tid; i < TT; i += 256) wgt[i] = wgtg[b * TT + i];
  __syncthreads();
  float acc = 0.f;
#pragma unroll 4
  for (int h = 0; h < HH; h++) {
    float hm = hvm[h];
    if (hm != 0.f) acc += hm * W_reinst0[((size_t)b * HH + h) * DD + d];
  }
#pragma unroll 4
  for (int s = 0; s < TT; s++) {
    float wv = wgt[s];
    if (wv != 0.f) acc += wv * x[((size_t)b * SFULL + s) * DD + d];
  }
  outp[BB * OO + b * DD + d] = acc;  // second output region
}

// ---------------------------------------------------------------------------
// Epilogue stage 3: mhn_out then out = mhn_out @ W_proj^T.
// ---------------------------------------------------------------------------
__global__ __launch_bounds__(1024) void epi3_kernel(const float* __restrict__ W_oh0,
                                                    const float* __restrict__ xVws,
                                                    const float* __restrict__ W_proj,
                                                    const float* __restrict__ hvmg,
                                                    const float* __restrict__ wgtg,
                                                    float* __restrict__ outp) {
  const int b = blockIdx.x;
  const int tid = threadIdx.x;
  const int w = tid >> 6, lane = tid & 63;
  __shared__ float hvm[HH];
  __shared__ float wgt[TT];
  __shared__ float mhn[VV];
  for (int i = tid; i < HH; i += 1024) hvm[i] = hvmg[b * HH + i];
  if (tid < TT) wgt[tid] = wgtg[b * TT + tid];
  __syncthreads();

  // term 1: untouched columns of W_oh0
  for (int v = w; v < VV; v += 16) {
    const float* p = W_oh0 + ((size_t)b * VV + v) * HH;
    float s = 0.f;
    for (int h = lane; h < HH; h += 64) s += hvm[h] * p[h];
#pragma unroll
    for (int off = 32; off; off >>= 1) s += __shfl_down(s, off);
    if (lane == 0) mhn[v] = s;
  }
  __syncthreads();
  // term 2: replaced columns = xv rows weighted by wgt
  if (tid < VV) {
    float s2 = 0.f;
#pragma unroll 4
    for (int s = 0; s < TT; s++) {
      float wv = wgt[s];
      if (wv != 0.f) s2 += wv * xVws[((size_t)b * TT + s) * VV + tid];
    }
    mhn[tid] += s2;
  }
  __syncthreads();
  // projection
  for (int o = w; o < OO; o += 16) {
    const float* p = W_proj + (size_t)o * VV;
    float s = 0.f;
    for (int v = lane; v < VV; v += 64) s += mhn[v] * p[v];
#pragma unroll
    for (int off = 32; off; off >>= 1) s += __shfl_down(s, off);
    if (lane == 0) outp[b * OO + o] = s;  // first output region
  }
}

// ---------------------------------------------------------------------------
extern "C" void kernel_launch(void* const* d_in, const int* in_sizes, int n_in,
                              void* d_out, int out_size, void* d_ws, size_t ws_size,
                              hipStream_t stream) {
  const float* x        = (const float*)d_in[0];
  const float* W_Q      = (const float*)d_in[1];
  const float* W_K      = (const float*)d_in[2];
  const float* W_V      = (const float*)d_in[3];
  const float* W_proj   = (const float*)d_in[4];
  const float* W_hi0    = (const float*)d_in[5];
  const float* W_oh0    = (const float*)d_in[6];
  const float* W_reinst0 = (const float*)d_in[7];
  float* outp = (float*)d_out;

  // workspace layout (bytes). L0t and Gram MUST be adjacent (scan computes
  // Gram addresses as an element offset from the L0 base pointer).
  char* ws = (char*)d_ws;
  double* L0t  = (double*)ws;                                  // 32*512*2048*8  = 268,435,456
  double* Gram = (double*)(ws + 268435456);                    // 32*512*512*8   = 67,108,864
  double* xK64 = (double*)(ws + 335544320);                    // 32*512*256*8   = 33,554,432
  float*  xVws = (float*)(ws + 369098752);                     // 32*512*256*4   = 16,777,216
  float*  xQws = (float*)(ws + 385875968);                     // 32*256*4       = 32,768
  int*    lastmap = (int*)(ws + 385908736);                    // 32*2048*4      = 262,144
  float*  hvmg = (float*)(ws + 386170880);                     // 32*2048*4      = 262,144
  float*  wgtg = (float*)(ws + 386433024);                     // 32*512*4       = 65,536
  (void)ws_size; (void)in_sizes; (void)n_in; (void)out_size;

  // 1) xK (fp64) = ctx @ W_K^T : per batch M=512, N=256, K=1024
  gemm128<float, float, double><<<dim3(KK / 128, TT / 128, BB), 256, 0, stream>>>(
      x, (long long)SFULL * DD, DD,
      W_K, 0LL, DD,
      xK64, (long long)TT * KK, KK, DD);

  // 2) xV (fp32) = ctx @ W_V^T
  gemm128<float, float, float><<<dim3(VV / 128, TT / 128, BB), 256, 0, stream>>>(
      x, (long long)SFULL * DD, DD,
      W_V, 0LL, DD,
      xVws, (long long)TT * VV, VV, DD);

  // 3) xQ
  xq_kernel<<<BB, 256, 0, stream>>>(x, W_Q, xQws, outp);

  // 4) L0t[b,t,h] = <xK[b,t], W_hi0[b,h]> : M=512, N=2048, K=256
  gemm128<double, float, double><<<dim3(HH / 128, TT / 128, BB), 256, 0, stream>>>(
      xK64, (long long)TT * KK, KK,
      W_hi0, (long long)HH * KK, KK,
      L0t, (long long)TT * HH, HH, KK);

  // 5) Gram[b,t,s] = <xK[b,t], xK[b,s]> : M=N=512, K=256
  gemm128<double, double, double><<<dim3(TT / 128, TT / 128, BB), 256, 0, stream>>>(
      xK64, (long long)TT * KK, KK,
      xK64, (long long)TT * KK, KK,
      Gram, (long long)TT * TT, TT, KK);

  // 6) sequential winner scan — one wave per batch, barrier-free
  scan_kernel<<<BB, 64, 0, stream>>>(L0t, Gram, lastmap);

  // 7) q-logits + softmax -> hvm, wgt
  epi1_kernel<<<BB, 1024, 0, stream>>>(W_hi0, xK64, xQws, lastmap, hvmg, wgtg);

  // 8) reinst_context
  epi2_kernel<<<dim3(DD / 256, BB), 256, 0, stream>>>(W_reinst0, x, hvmg, wgtg, outp);

  // 9) mhn_out + projection
  epi3_kernel<<<BB, 1024, 0, stream>>>(W_oh0, xVws, W_proj, hvmg, wgtg, outp);
}